// Round 10
// baseline (536.244 us; speedup 1.0000x reference)
//
#include <hip/hip_runtime.h>
#include <hip/hip_bf16.h>

#define T_TOK 4096
#define DM 1024
#define DH 4096
#define NE 8
#define NSLOT (T_TOK * 2)
#define NSLOT_PAD (NSLOT + NE * 256)  // 10240: expert bases 256-aligned
#define T256 40                        // 256-tiles: 8192/256 + 8
#define T128 80
#define WELEMS ((size_t)NE * DH * DM)

typedef __attribute__((ext_vector_type(4))) float fl4;
typedef __attribute__((ext_vector_type(8))) short sh8;
typedef __attribute__((ext_vector_type(8))) unsigned short us8;
typedef unsigned short u16;

__device__ __forceinline__ u16 f2bf(float f) {
  __hip_bfloat16 h = __float2bfloat16(f);
  return __builtin_bit_cast(u16, h);
}

__device__ __forceinline__ float gelu_tanh(float x) {
  float x3 = x * x * x;
  float u = 0.7978845608028654f * (x + 0.044715f * x3);
  return 0.5f * x * (1.0f + tanhf(u));
}

__device__ __forceinline__ void gload_lds16(const void* g, void* l) {
  __builtin_amdgcn_global_load_lds(
      (const __attribute__((address_space(1))) unsigned int*)g,
      (__attribute__((address_space(3))) unsigned int*)l, 16, 0, 0);
}

template <int N>
__device__ __forceinline__ void wait_vmcnt() {
  if constexpr (N == 0) asm volatile("s_waitcnt vmcnt(0)" ::: "memory");
  else if constexpr (N == 3) asm volatile("s_waitcnt vmcnt(3)" ::: "memory");
  else if constexpr (N == 4) asm volatile("s_waitcnt vmcnt(4)" ::: "memory");
}

// ---------------- weight fp32 -> bf16 ----------------
__global__ __launch_bounds__(256) void wconv_kernel(
    const float* __restrict__ w1, const float* __restrict__ w2,
    u16* __restrict__ w1b, u16* __restrict__ w2b) {
  size_t stride = (size_t)gridDim.x * 256 * 8;
  for (size_t i = ((size_t)blockIdx.x * 256 + threadIdx.x) * 8; i < WELEMS; i += stride) {
    fl4 a0 = *(const fl4*)(w1 + i);
    fl4 a1 = *(const fl4*)(w1 + i + 4);
    fl4 b0 = *(const fl4*)(w2 + i);
    fl4 b1 = *(const fl4*)(w2 + i + 4);
    us8 oa, ob;
#pragma unroll
    for (int j = 0; j < 4; j++) {
      oa[j] = f2bf(a0[j]); oa[j + 4] = f2bf(a1[j]);
      ob[j] = f2bf(b0[j]); ob[j + 4] = f2bf(b1[j]);
    }
    *(us8*)(w1b + i) = oa;
    *(us8*)(w2b + i) = ob;
  }
}

// ---------------- router ----------------
__global__ __launch_bounds__(256) void router_kernel(
    const float* __restrict__ x, const float* __restrict__ rw,
    u16* __restrict__ xbf, int* __restrict__ tok_e, float* __restrict__ tok_w,
    int* __restrict__ ctl) {
  int tid = threadIdx.x;
  int wv = tid >> 6, lane = tid & 63;
  int t = blockIdx.x * 4 + wv;
  if (t >= T_TOK) return;

  const float* xp = x + (size_t)t * DM + lane * 16;
  fl4 xq[4];
#pragma unroll
  for (int i = 0; i < 4; i++) xq[i] = *(const fl4*)(xp + i * 4);

  float acc8[NE];
#pragma unroll
  for (int e = 0; e < NE; e++) {
    const float* wp = rw + (size_t)e * DM + lane * 16;
    float s = 0.f;
#pragma unroll
    for (int i = 0; i < 4; i++) {
      fl4 w4 = *(const fl4*)(wp + i * 4);
      s += xq[i][0] * w4[0] + xq[i][1] * w4[1] + xq[i][2] * w4[2] + xq[i][3] * w4[3];
    }
    acc8[e] = s;
  }
  us8 h0, h1;
#pragma unroll
  for (int i = 0; i < 8; i++) {
    h0[i] = f2bf(xq[i >> 2][i & 3]);
    h1[i] = f2bf(xq[2 + (i >> 2)][i & 3]);
  }
  *(us8*)(xbf + (size_t)t * DM + lane * 16) = h0;
  *(us8*)(xbf + (size_t)t * DM + lane * 16 + 8) = h1;

#pragma unroll
  for (int e = 0; e < NE; e++) {
#pragma unroll
    for (int off = 32; off > 0; off >>= 1) acc8[e] += __shfl_xor(acc8[e], off);
  }

  if (lane == 0) {
    float v1 = -1e30f, v2 = -1e30f;
    int i1 = 0, i2 = 0;
#pragma unroll
    for (int e = 0; e < NE; e++) {
      float v = acc8[e];
      if (v > v1) { v2 = v1; i2 = i1; v1 = v; i1 = e; }
      else if (v > v2) { v2 = v; i2 = e; }
    }
    float ex = expf(v2 - v1);
    float s = 1.0f + ex;
    tok_e[t * 2] = i1; tok_e[t * 2 + 1] = i2;
    tok_w[t * 2] = 1.0f / s; tok_w[t * 2 + 1] = ex / s;
    atomicAdd(&ctl[i1], 1);
    atomicAdd(&ctl[i2], 1);
  }
}

// ctl: [0..7] counts, [8..15] cursors, [16..23] bases (256-aligned),
// [32..71] tile256_expert, [72..151] tile128_expert
__global__ __launch_bounds__(128) void scan_kernel(int* __restrict__ ctl) {
  __shared__ int base_s[NE];
  __shared__ int tb_s[NE + 1];
  int tid = threadIdx.x;
  if (tid == 0) {
    int s = 0, tb = 0;
    for (int e = 0; e < NE; e++) {
      base_s[e] = s;
      tb_s[e] = tb;
      int nte = (ctl[e] + 255) >> 8;
      tb += nte;
      s += nte << 8;
    }
    tb_s[NE] = tb;
  }
  __syncthreads();
  if (tid < NE) { ctl[16 + tid] = base_s[tid]; ctl[8 + tid] = base_s[tid]; }
  if (tid < T256) {
    int e = -1;
#pragma unroll
    for (int k = 0; k < NE; k++)
      if (tid >= tb_s[k] && tid < tb_s[k + 1]) e = k;
    ctl[32 + tid] = e;
  }
  if (tid < T128) {
    int e = -1;
#pragma unroll
    for (int k = 0; k < NE; k++)
      if (tid >= 2 * tb_s[k] && tid < 2 * tb_s[k + 1]) e = k;
    ctl[72 + tid] = e;
  }
}

__global__ __launch_bounds__(256) void assign_kernel(
    const int* __restrict__ tok_e, const float* __restrict__ tok_w,
    int* __restrict__ ctl, int* __restrict__ tok_map, float* __restrict__ pair_w,
    int* __restrict__ islot) {
  int t = blockIdx.x * 256 + threadIdx.x;
  if (t < T_TOK) {
#pragma unroll
    for (int k = 0; k < 2; k++) {
      int e = tok_e[t * 2 + k];
      int slot = atomicAdd(&ctl[8 + e], 1);
      tok_map[slot] = t;
      pair_w[slot] = tok_w[t * 2 + k];
      islot[t * 2 + k] = slot;
    }
  }
}

// ---------------- combine: out[t] = sum_k w_k * (y[slot_k] + b2[e_k]) ----------
__global__ __launch_bounds__(256) void combine_kernel(
    const float* __restrict__ y, const float* __restrict__ b2,
    const int* __restrict__ tok_e, const int* __restrict__ islot,
    const float* __restrict__ tok_w, float* __restrict__ out) {
  int idx = blockIdx.x * 256 + threadIdx.x;
  int t = idx >> 8;
  int c4 = (idx & 255) * 4;
  int e0 = tok_e[t * 2], e1 = tok_e[t * 2 + 1];
  int s0 = islot[t * 2], s1 = islot[t * 2 + 1];
  float w0 = tok_w[t * 2], w1 = tok_w[t * 2 + 1];
  fl4 y0 = *(const fl4*)(y + (size_t)s0 * DM + c4);
  fl4 y1 = *(const fl4*)(y + (size_t)s1 * DM + c4);
  fl4 bb0 = *(const fl4*)(b2 + (size_t)e0 * DM + c4);
  fl4 bb1 = *(const fl4*)(b2 + (size_t)e1 * DM + c4);
  fl4 o;
#pragma unroll
  for (int i = 0; i < 4; i++) o[i] = w0 * (y0[i] + bb0[i]) + w1 * (y1[i] + bb1[i]);
  *(fl4*)(out + (size_t)t * DM + c4) = o;
}

// ---- grouped GEMM: big tiles, 512 thr (8 waves), 3-buf distance-2 pipeline ---
// fc1: BM=256 x BN=256 (wave out 128x64, 8x4 frags); fc2: BM=128 x BN=256
// (wave out 64x64... wr halves M, wc quarters N). Same race-verified ITER as
// r9: vmcnt(SPI) drains the stage issued 2 K-steps ago; one barrier/K-step.
// Epilogue: LDS repack (2 col-halves) -> coalesced dwordx4 stores.
template <bool FC1>
__global__ __launch_bounds__(512, 2) void moe_gemm(
    const u16* __restrict__ Abase, const u16* __restrict__ Wb,
    const float* __restrict__ bias, u16* __restrict__ Hout,
    float* __restrict__ Yout, const int* __restrict__ tok_map,
    const int* __restrict__ ctl) {
  constexpr int BM = FC1 ? 256 : 128;
  constexpr int KTOT = FC1 ? DM : DH;
  constexpr int NTOT = FC1 ? DH : DM;
  constexpr int TILES = FC1 ? T256 : T128;
  constexpr int XT = TILES / 8;
  constexpr int NK = KTOT / 32;
  constexpr int MF = BM / 32;     // M frags per wave: 8 / 4
  constexpr int APT = BM / 128;   // A gloads per thread per stage: 2 / 1
  constexpr int SPI = APT + 2;    // stage VMEM instr per iter (vmcnt target)
  constexpr int ABUF = BM * 64;   // A buffer bytes
  constexpr int BBUF = 256 * 64;

  __shared__ char lds[3 * (ABUF + BBUF)];
  char* Asb = lds;
  char* Bsb = lds + 3 * ABUF;

  int bid = blockIdx.x;
  int x = bid & 7, idx = bid >> 3;
  int nt, tl;
  if (FC1) { nt = idx & 15; tl = idx >> 4; }
  else     { nt = idx & 3;  tl = idx >> 2; }
  int tile = x * XT + tl;

  int e = ctl[(FC1 ? 32 : 72) + tile];
  if (e < 0) return;
  int cnt = ctl[e], base = ctl[16 + e];
  int rowlim = base + cnt;
  int m0 = tile * BM;

  int tid = threadIdx.x;
  int wv = tid >> 6, lane = tid & 63;
  int wr = wv >> 2, wc = wv & 3;
  int khalf = lane >> 4, l15 = lane & 15;

  const u16* asrc[APT];
  const u16* bsrc[2];
#pragma unroll
  for (int r = 0; r < APT; r++) {
    int c = r * 512 + tid;
    int row = c >> 2, q = c & 3;
    int qs = q ^ ((row >> 2) & 3);
    int slot = m0 + row;
    size_t arow;
    if (FC1)
      arow = (slot < rowlim) ? (size_t)tok_map[slot] : 0;
    else
      arow = (size_t)slot;  // H has NSLOT_PAD rows; garbage rows masked on store
    asrc[r] = Abase + arow * KTOT + qs * 8;
  }
#pragma unroll
  for (int r = 0; r < 2; r++) {
    int c = r * 512 + tid;
    int row = c >> 2, q = c & 3;
    int qs = q ^ ((row >> 2) & 3);
    bsrc[r] = Wb + ((size_t)e * NTOT + nt * 256 + row) * KTOT + qs * 8;
  }

#define STAGE(B, KT)                                                          \
  { _Pragma("unroll") for (int r = 0; r < APT; r++)                           \
      gload_lds16(asrc[r] + (KT) * 32, Asb + (B) * ABUF + (r * 512 + wv * 64) * 16); \
    _Pragma("unroll") for (int r = 0; r < 2; r++)                             \
      gload_lds16(bsrc[r] + (KT) * 32, Bsb + (B) * BBUF + (r * 512 + wv * 64) * 16); }

  int aoff[MF], boff[4];
#pragma unroll
  for (int m = 0; m < MF; m++) {
    int rowl = wr * (BM / 2) + m * 16 + l15;
    aoff[m] = rowl * 64 + ((khalf * 16) ^ ((rowl & 12) << 2));
  }
#pragma unroll
  for (int n = 0; n < 4; n++) {
    int coll = wc * 64 + n * 16 + l15;
    boff[n] = coll * 64 + ((khalf * 16) ^ ((coll & 12) << 2));
  }

  fl4 acc[MF][4];
#pragma unroll
  for (int m = 0; m < MF; m++)
#pragma unroll
    for (int n = 0; n < 4; n++) acc[m][n] = (fl4){0.f, 0.f, 0.f, 0.f};

#define ITER(B, KT)                                                           \
  if ((KT) < NK) {                                                            \
    wait_vmcnt<SPI>();                                                        \
    __builtin_amdgcn_s_barrier();                                             \
    __builtin_amdgcn_sched_barrier(0);                                        \
    sh8 af[MF], bfr[4];                                                       \
    _Pragma("unroll") for (int m = 0; m < MF; m++)                            \
      af[m] = *(const sh8*)(Asb + (B) * ABUF + aoff[m]);                      \
    _Pragma("unroll") for (int n = 0; n < 4; n++)                             \
      bfr[n] = *(const sh8*)(Bsb + (B) * BBUF + boff[n]);                     \
    {                                                                         \
      int knext = ((KT) + 2 < NK) ? (KT) + 2 : NK - 1;                        \
      STAGE(((B) + 2) % 3, knext);                                            \
    }                                                                         \
    __builtin_amdgcn_s_setprio(1);                                            \
    _Pragma("unroll") for (int m = 0; m < MF; m++)                            \
    _Pragma("unroll") for (int n = 0; n < 4; n++)                             \
      acc[m][n] = __builtin_amdgcn_mfma_f32_16x16x32_bf16(af[m], bfr[n],      \
                                                          acc[m][n], 0, 0, 0); \
    __builtin_amdgcn_s_setprio(0);                                            \
  }

  STAGE(0, 0);
  STAGE(1, 1);
  for (int kt = 0; kt < NK; kt += 3) {
    ITER(0, kt);
    ITER(1, kt + 1);
    ITER(2, kt + 2);
  }
  wait_vmcnt<0>();
  __builtin_amdgcn_s_barrier();  // all waves done reading LDS tiles

  // -------- epilogue: LDS repack in 2 column halves, coalesced stores -------
  float bn[4];
  if (FC1) {
#pragma unroll
    for (int n = 0; n < 4; n++)
      bn[n] = bias[(size_t)e * NTOT + nt * 256 + wc * 64 + n * 16 + l15];
  }
#pragma unroll
  for (int h = 0; h < 2; h++) {
    if ((wc >> 1) == h) {
      if (FC1) {
        u16* t16 = (u16*)lds;
#pragma unroll
        for (int m = 0; m < MF; m++)
#pragma unroll
          for (int n = 0; n < 4; n++)
#pragma unroll
            for (int j = 0; j < 4; j++) {
              int row = wr * (BM / 2) + m * 16 + khalf * 4 + j;
              t16[row * 128 + (wc & 1) * 64 + n * 16 + l15] =
                  f2bf(gelu_tanh(acc[m][n][j] + bn[n]));
            }
      } else {
        float* t32 = (float*)lds;
#pragma unroll
        for (int m = 0; m < MF; m++)
#pragma unroll
          for (int n = 0; n < 4; n++)
#pragma unroll
            for (int j = 0; j < 4; j++) {
              int row = wr * (BM / 2) + m * 16 + khalf * 4 + j;
              t32[row * 128 + (wc & 1) * 64 + n * 16 + l15] = acc[m][n][j];
            }
      }
    }
    asm volatile("s_waitcnt lgkmcnt(0)" ::: "memory");
    __builtin_amdgcn_s_barrier();
    if (FC1) {
      const u16* t16 = (const u16*)lds;
#pragma unroll
      for (int r = 0; r < 8; r++) {
        int c = r * 512 + tid;          // BM*16 chunks = 4096
        int row = c >> 4, ch = c & 15;
        if (m0 + row < rowlim) {
          sh8 v = *(const sh8*)(t16 + row * 128 + ch * 8);
          *(sh8*)(Hout + (size_t)(m0 + row) * DH + nt * 256 + h * 128 + ch * 8) = v;
        }
      }
    } else {
#pragma unroll
      for (int r = 0; r < 8; r++) {
        int c = r * 512 + tid;          // BM*32 chunks = 4096
        int row = c >> 5, ch = c & 31;
        if (m0 + row < rowlim) {
          fl4 v = *(const fl4*)((const float*)lds + row * 128 + ch * 4);
          *(fl4*)(Yout + (size_t)(m0 + row) * DM + nt * 256 + h * 128 + ch * 4) = v;
        }
      }
    }
    if (h == 0) {
      asm volatile("s_waitcnt lgkmcnt(0)" ::: "memory");
      __builtin_amdgcn_s_barrier();
    }
  }
#undef STAGE
#undef ITER
}

extern "C" void kernel_launch(void* const* d_in, const int* in_sizes, int n_in,
                              void* d_out, int out_size, void* d_ws, size_t ws_size,
                              hipStream_t stream) {
  const float* x  = (const float*)d_in[0];
  const float* rw = (const float*)d_in[1];
  const float* w1 = (const float*)d_in[2];
  const float* b1 = (const float*)d_in[3];
  const float* w2 = (const float*)d_in[4];
  const float* b2 = (const float*)d_in[5];
  float* out = (float*)d_out;

  char* ws = (char*)d_ws;
  size_t off = 0;
  u16* xbf = (u16*)(ws + off); off += (size_t)T_TOK * DM * 2;
  u16* H   = (u16*)(ws + off); off += (size_t)NSLOT_PAD * DH * 2;
  u16* w1b = (u16*)(ws + off); off += WELEMS * 2;
  u16* w2b = (u16*)(ws + off); off += WELEMS * 2;
  int* tok_map  = (int*)(ws + off); off += (size_t)NSLOT_PAD * 4;
  float* pair_w = (float*)(ws + off); off += (size_t)NSLOT_PAD * 4;
  int* tok_e    = (int*)(ws + off); off += (size_t)T_TOK * 8;
  float* tok_w  = (float*)(ws + off); off += (size_t)T_TOK * 8;
  int* islot    = (int*)(ws + off); off += (size_t)T_TOK * 8;
  int* ctl      = (int*)(ws + off); off += 1024;
  // y (fp32, NSLOT_PAD x DM = 40 MB) overlays w1b (64 MB, dead after fc1)
  float* y = (float*)w1b;

  hipMemsetAsync(ctl, 0, 160 * 4, stream);

  router_kernel<<<T_TOK / 4, 256, 0, stream>>>(x, rw, xbf, tok_e, tok_w, ctl);
  scan_kernel<<<1, 128, 0, stream>>>(ctl);
  assign_kernel<<<T_TOK / 256, 256, 0, stream>>>(tok_e, tok_w, ctl, tok_map, pair_w, islot);
  wconv_kernel<<<8192, 256, 0, stream>>>(w1, w2, w1b, w2b);

  moe_gemm<true><<<T256 * (DH / 256), 512, 0, stream>>>(
      xbf, w1b, b1, H, nullptr, tok_map, ctl);
  moe_gemm<false><<<T128 * (DM / 256), 512, 0, stream>>>(
      H, w2b, nullptr, nullptr, y, tok_map, ctl);
  combine_kernel<<<T_TOK * DM / 4 / 256, 256, 0, stream>>>(
      y, b2, tok_e, islot, tok_w, out);
}

// Round 11
// 518.316 us; speedup vs baseline: 1.0346x; 1.0346x over previous
//
#include <hip/hip_runtime.h>
#include <hip/hip_bf16.h>

#define T_TOK 4096
#define DM 1024
#define DH 4096
#define NE 8
#define NSLOT (T_TOK * 2)
#define NSLOT_PAD (NSLOT + NE * 128)  // 9216: expert bases 128-aligned
#define MAXTILES 72
#define WELEMS ((size_t)NE * DH * DM)

typedef __attribute__((ext_vector_type(4))) float fl4;
typedef __attribute__((ext_vector_type(8))) short sh8;
typedef __attribute__((ext_vector_type(8))) unsigned short us8;
typedef unsigned short u16;

__device__ __forceinline__ u16 f2bf(float f) {
  __hip_bfloat16 h = __float2bfloat16(f);
  return __builtin_bit_cast(u16, h);
}

__device__ __forceinline__ float gelu_tanh(float x) {
  float x3 = x * x * x;
  float u = 0.7978845608028654f * (x + 0.044715f * x3);
  return 0.5f * x * (1.0f + tanhf(u));
}

__device__ __forceinline__ void gload_lds16(const void* g, void* l) {
  __builtin_amdgcn_global_load_lds(
      (const __attribute__((address_space(1))) unsigned int*)g,
      (__attribute__((address_space(3))) unsigned int*)l, 16, 0, 0);
}

// ---------------- weight fp32 -> bf16 (one tensor) ----------------
__global__ __launch_bounds__(256) void wconv_kernel(
    const float* __restrict__ w, u16* __restrict__ wb) {
  size_t stride = (size_t)gridDim.x * 256 * 8;
  for (size_t i = ((size_t)blockIdx.x * 256 + threadIdx.x) * 8; i < WELEMS; i += stride) {
    fl4 a0 = *(const fl4*)(w + i);
    fl4 a1 = *(const fl4*)(w + i + 4);
    us8 oa;
#pragma unroll
    for (int j = 0; j < 4; j++) { oa[j] = f2bf(a0[j]); oa[j + 4] = f2bf(a1[j]); }
    *(us8*)(wb + i) = oa;
  }
}

// ---------------- router ----------------
__global__ __launch_bounds__(256) void router_kernel(
    const float* __restrict__ x, const float* __restrict__ rw,
    u16* __restrict__ xbf, int* __restrict__ tok_e, float* __restrict__ tok_w,
    int* __restrict__ ctl) {
  int tid = threadIdx.x;
  int wv = tid >> 6, lane = tid & 63;
  int t = blockIdx.x * 4 + wv;
  if (t >= T_TOK) return;

  const float* xp = x + (size_t)t * DM + lane * 16;
  fl4 xq[4];
#pragma unroll
  for (int i = 0; i < 4; i++) xq[i] = *(const fl4*)(xp + i * 4);

  float acc8[NE];
#pragma unroll
  for (int e = 0; e < NE; e++) {
    const float* wp = rw + (size_t)e * DM + lane * 16;
    float s = 0.f;
#pragma unroll
    for (int i = 0; i < 4; i++) {
      fl4 w4 = *(const fl4*)(wp + i * 4);
      s += xq[i][0] * w4[0] + xq[i][1] * w4[1] + xq[i][2] * w4[2] + xq[i][3] * w4[3];
    }
    acc8[e] = s;
  }
  us8 h0, h1;
#pragma unroll
  for (int i = 0; i < 8; i++) {
    h0[i] = f2bf(xq[i >> 2][i & 3]);
    h1[i] = f2bf(xq[2 + (i >> 2)][i & 3]);
  }
  *(us8*)(xbf + (size_t)t * DM + lane * 16) = h0;
  *(us8*)(xbf + (size_t)t * DM + lane * 16 + 8) = h1;

#pragma unroll
  for (int e = 0; e < NE; e++) {
#pragma unroll
    for (int off = 32; off > 0; off >>= 1) acc8[e] += __shfl_xor(acc8[e], off);
  }

  if (lane == 0) {
    float v1 = -1e30f, v2 = -1e30f;
    int i1 = 0, i2 = 0;
#pragma unroll
    for (int e = 0; e < NE; e++) {
      float v = acc8[e];
      if (v > v1) { v2 = v1; i2 = i1; v1 = v; i1 = e; }
      else if (v > v2) { v2 = v; i2 = e; }
    }
    float ex = expf(v2 - v1);
    float s = 1.0f + ex;
    tok_e[t * 2] = i1; tok_e[t * 2 + 1] = i2;
    tok_w[t * 2] = 1.0f / s; tok_w[t * 2 + 1] = ex / s;
    atomicAdd(&ctl[i1], 1);
    atomicAdd(&ctl[i2], 1);
  }
}

// ctl: [0..7] counts, [8..15] cursors, [16..23] bases (128-aligned), [32..103] tile_expert
__global__ __launch_bounds__(128) void scan_kernel(int* __restrict__ ctl) {
  __shared__ int base_s[NE];
  __shared__ int tb_s[NE + 1];
  int tid = threadIdx.x;
  if (tid == 0) {
    int s = 0, tb = 0;
    for (int e = 0; e < NE; e++) {
      base_s[e] = s;
      tb_s[e] = tb;
      int nte = (ctl[e] + 127) >> 7;
      tb += nte;
      s += nte << 7;
    }
    tb_s[NE] = tb;
  }
  __syncthreads();
  if (tid < NE) { ctl[16 + tid] = base_s[tid]; ctl[8 + tid] = base_s[tid]; }
  if (tid < MAXTILES) {
    int e = -1;
#pragma unroll
    for (int k = 0; k < NE; k++)
      if (tid >= tb_s[k] && tid < tb_s[k + 1]) e = k;
    ctl[32 + tid] = e;
  }
}

__global__ __launch_bounds__(256) void assign_kernel(
    const int* __restrict__ tok_e, int* __restrict__ ctl,
    int* __restrict__ tok_map, int* __restrict__ islot) {
  int t = blockIdx.x * 256 + threadIdx.x;
  if (t < T_TOK) {
#pragma unroll
    for (int k = 0; k < 2; k++) {
      int e = tok_e[t * 2 + k];
      int slot = atomicAdd(&ctl[8 + e], 1);
      tok_map[slot] = t;
      islot[t * 2 + k] = slot;
    }
  }
}

// ---------------- gather: xg[slot] = xbf[tok_map[slot]] (linearize A) --------
__global__ __launch_bounds__(256) void gather_kernel(
    const u16* __restrict__ xbf, const int* __restrict__ tok_map,
    u16* __restrict__ xg) {
  int slot = blockIdx.x * 2 + (threadIdx.x >> 7);
  int li = threadIdx.x & 127;
  int t = tok_map[slot];  // pad slots memset to 0 -> token 0 (masked later)
  *(us8*)(xg + (size_t)slot * DM + li * 8) =
      *(const us8*)(xbf + (size_t)t * DM + li * 8);
}

// ---------------- combine: out[t] = sum_k w_k * (y[slot_k] + b2[e_k]) --------
__global__ __launch_bounds__(256) void combine_kernel(
    const float* __restrict__ y, const float* __restrict__ b2,
    const int* __restrict__ tok_e, const int* __restrict__ islot,
    const float* __restrict__ tok_w, float* __restrict__ out) {
  int idx = blockIdx.x * 256 + threadIdx.x;
  int t = idx >> 8;
  int c4 = (idx & 255) * 4;
  int e0 = tok_e[t * 2], e1 = tok_e[t * 2 + 1];
  int s0 = islot[t * 2], s1 = islot[t * 2 + 1];
  float w0 = tok_w[t * 2], w1 = tok_w[t * 2 + 1];
  fl4 y0 = *(const fl4*)(y + (size_t)s0 * DM + c4);
  fl4 y1 = *(const fl4*)(y + (size_t)s1 * DM + c4);
  fl4 bb0 = *(const fl4*)(b2 + (size_t)e0 * DM + c4);
  fl4 bb1 = *(const fl4*)(b2 + (size_t)e1 * DM + c4);
  fl4 o;
#pragma unroll
  for (int i = 0; i < 4; i++) o[i] = w0 * (y0[i] + bb0[i]) + w1 * (y1[i] + bb1[i]);
  *(fl4*)(out + (size_t)t * DM + c4) = o;
}

// ---- grouped GEMM: 128x128, BK=32, 4 waves, r8 counted-vmcnt dbuf loop ------
// A is LINEAR for both GEMMs (fc1: pre-gathered xg; fc2: H slots).
// fc2 is K-split 2-way (ks in {0,1}, K=2048 each) -> 1152 blocks (~4.5/CU);
// partials atomicAdd into pre-zeroed fp32 y.
template <bool FC1>
__global__ __launch_bounds__(256, 4) void moe_gemm(
    const u16* __restrict__ Ab, const u16* __restrict__ Wb,
    const float* __restrict__ bias, u16* __restrict__ Hout,
    float* __restrict__ Yout, const int* __restrict__ ctl) {
  constexpr int KTOT = FC1 ? DM : DH;
  constexpr int NTOT = FC1 ? DH : DM;
  constexpr int NKL = FC1 ? 32 : 64;  // local K-steps (fc2: half of K=4096)

  int bid = blockIdx.x;
  int x = bid & 7, idx = bid >> 3;
  int tl = idx % 9, pn = idx / 9;
  int nt, ks;
  if (FC1) { nt = pn; ks = 0; }
  else     { nt = pn >> 1; ks = pn & 1; }
  int tile = x * 9 + tl;

  int e = ctl[32 + tile];
  if (e < 0) return;
  int cnt = ctl[e], base = ctl[16 + e];
  int rowlim = base + cnt;
  int m0 = tile * 128;

  __shared__ u16 As[2][128 * 32];
  __shared__ u16 Bs[2][128 * 32];

  int tid = threadIdx.x;
  int wv = tid >> 6, lane = tid & 63;
  int wr = wv >> 1, wc = wv & 1;
  int khalf = lane >> 4, l15 = lane & 15;

  const u16* asrc[2];
  const u16* bsrc[2];
#pragma unroll
  for (int r2 = 0; r2 < 2; r2++) {
    int c = r2 * 256 + tid;
    int row = c >> 2, q = c & 3;
    int qs = q ^ ((row >> 2) & 3);
    asrc[r2] = Ab + (size_t)(m0 + row) * KTOT + ks * 2048 + qs * 8;
    bsrc[r2] = Wb + ((size_t)e * NTOT + nt * 128 + row) * KTOT + ks * 2048 + qs * 8;
  }

#define STAGE(B, KT)                                                         \
  { _Pragma("unroll") for (int r2 = 0; r2 < 2; r2++) {                       \
      gload_lds16(asrc[r2] + (KT) * 32, &As[B][(r2 * 256 + wv * 64) * 8]);   \
      gload_lds16(bsrc[r2] + (KT) * 32, &Bs[B][(r2 * 256 + wv * 64) * 8]);   \
    } }

  int aoff[4], boff[4];
#pragma unroll
  for (int m = 0; m < 4; m++) {
    int rowl = wr * 64 + m * 16 + l15;
    aoff[m] = rowl * 64 + ((khalf * 16) ^ ((rowl & 12) << 2));
  }
#pragma unroll
  for (int n = 0; n < 4; n++) {
    int coll = wc * 64 + n * 16 + l15;
    boff[n] = coll * 64 + ((khalf * 16) ^ ((coll & 12) << 2));
  }

  fl4 acc[4][4];
#pragma unroll
  for (int m = 0; m < 4; m++)
#pragma unroll
    for (int n = 0; n < 4; n++) acc[m][n] = (fl4){0.f, 0.f, 0.f, 0.f};

#define COMPUTE(B)                                                           \
  {                                                                          \
    sh8 af[4], bfr[4];                                                       \
    _Pragma("unroll") for (int m = 0; m < 4; m++)                            \
      af[m] = *(const sh8*)((const char*)As[B] + aoff[m]);                   \
    _Pragma("unroll") for (int n = 0; n < 4; n++)                            \
      bfr[n] = *(const sh8*)((const char*)Bs[B] + boff[n]);                  \
    __builtin_amdgcn_s_setprio(1);                                           \
    _Pragma("unroll") for (int m = 0; m < 4; m++)                            \
    _Pragma("unroll") for (int n = 0; n < 4; n++)                            \
      acc[m][n] = __builtin_amdgcn_mfma_f32_16x16x32_bf16(af[m], bfr[n],     \
                                                          acc[m][n], 0, 0, 0); \
    __builtin_amdgcn_s_setprio(0);                                           \
  }

  STAGE(0, 0);
  for (int kt = 0; kt < NKL; kt += 2) {
    STAGE(1, kt + 1);
    asm volatile("s_waitcnt vmcnt(4)" ::: "memory");
    __builtin_amdgcn_s_barrier();
    COMPUTE(0);
    __builtin_amdgcn_s_barrier();
    if (kt + 2 < NKL) {
      STAGE(0, kt + 2);
      asm volatile("s_waitcnt vmcnt(4)" ::: "memory");
    } else {
      asm volatile("s_waitcnt vmcnt(0)" ::: "memory");
    }
    __builtin_amdgcn_s_barrier();
    COMPUTE(1);
    __builtin_amdgcn_s_barrier();
  }

  if (FC1) {
#pragma unroll
    for (int n = 0; n < 4; n++) {
      int colg = nt * 128 + wc * 64 + n * 16 + l15;
      float bn = bias[(size_t)e * DH + colg];
#pragma unroll
      for (int m = 0; m < 4; m++) {
#pragma unroll
        for (int j = 0; j < 4; j++) {
          int slot = m0 + wr * 64 + m * 16 + khalf * 4 + j;
          if (slot < rowlim) {
            float v = acc[m][n][j] + bn;
            Hout[(size_t)slot * DH + colg] = f2bf(gelu_tanh(v));
          }
        }
      }
    }
  } else {
#pragma unroll
    for (int m = 0; m < 4; m++) {
#pragma unroll
      for (int j = 0; j < 4; j++) {
        int slot = m0 + wr * 64 + m * 16 + khalf * 4 + j;
        if (slot < rowlim) {
#pragma unroll
          for (int n = 0; n < 4; n++) {
            int colg = nt * 128 + wc * 64 + n * 16 + l15;
            atomicAdd(&Yout[(size_t)slot * DM + colg], acc[m][n][j]);
          }
        }
      }
    }
  }
#undef STAGE
#undef COMPUTE
}

extern "C" void kernel_launch(void* const* d_in, const int* in_sizes, int n_in,
                              void* d_out, int out_size, void* d_ws, size_t ws_size,
                              hipStream_t stream) {
  const float* x  = (const float*)d_in[0];
  const float* rw = (const float*)d_in[1];
  const float* w1 = (const float*)d_in[2];
  const float* b1 = (const float*)d_in[3];
  const float* w2 = (const float*)d_in[4];
  const float* b2 = (const float*)d_in[5];
  float* out = (float*)d_out;

  char* ws = (char*)d_ws;
  size_t off = 0;
  u16* xbf = (u16*)(ws + off); off += (size_t)T_TOK * DM * 2;
  u16* H   = (u16*)(ws + off); off += (size_t)NSLOT_PAD * DH * 2;
  u16* w1b = (u16*)(ws + off); off += WELEMS * 2;
  u16* w2b = (u16*)(ws + off); off += WELEMS * 2;
  int* tok_map  = (int*)(ws + off); off += (size_t)NSLOT_PAD * 4;
  int* tok_e    = (int*)(ws + off); off += (size_t)T_TOK * 8;
  float* tok_w  = (float*)(ws + off); off += (size_t)T_TOK * 8;
  int* islot    = (int*)(ws + off); off += (size_t)T_TOK * 8;
  int* ctl      = (int*)(ws + off); off += 512;
  // overlays: xg (19 MB) over w2b (w2 converted AFTER fc1);
  //           y  (37.7 MB fp32) over w1b (dead after fc1)
  u16* xg = w2b;
  float* y = (float*)w1b;

  hipMemsetAsync(ctl, 0, 128 * 4, stream);
  hipMemsetAsync(tok_map, 0, (size_t)NSLOT_PAD * 4, stream);

  router_kernel<<<T_TOK / 4, 256, 0, stream>>>(x, rw, xbf, tok_e, tok_w, ctl);
  scan_kernel<<<1, 128, 0, stream>>>(ctl);
  assign_kernel<<<T_TOK / 256, 256, 0, stream>>>(tok_e, ctl, tok_map, islot);
  gather_kernel<<<NSLOT_PAD / 2, 256, 0, stream>>>(xbf, tok_map, xg);
  wconv_kernel<<<4096, 256, 0, stream>>>(w1, w1b);

  moe_gemm<true><<<8 * 9 * 32, 256, 0, stream>>>(xg, w1b, b1, H, nullptr, ctl);

  hipMemsetAsync(y, 0, (size_t)NSLOT_PAD * DM * 4, stream);   // w1b dead
  wconv_kernel<<<4096, 256, 0, stream>>>(w2, w2b);            // overwrites xg (dead)

  moe_gemm<false><<<8 * 9 * 16, 256, 0, stream>>>(H, w2b, nullptr, nullptr, y, ctl);
  combine_kernel<<<T_TOK * DM / 4 / 256, 256, 0, stream>>>(
      y, b2, tok_e, islot, tok_w, out);
}